// Round 4
// baseline (406.206 us; speedup 1.0000x reference)
//
#include <hip/hip_runtime.h>

#define B 8
#define F 16
#define K 24
#define L 147456            // 384*384
#define CHUNK 1024          // pixels per block in kA/kB (256 thr x 4 px)
#define NCHUNK (L / CHUNK)  // 144
#define NSEG (L / 256)      // 576, kC: 1 px/thread
#define EPSF 1e-8f
#define DELTA_VAR 0.5f
#define DELTA_DIST 1.5f
#define GAMMA 0.001f

typedef float fx4 __attribute__((ext_vector_type(4)));

// Workspace layout (bytes):
//   0      : sums    float[B][F][K]   (12288)
//   12288  : counts  float[B][K]      (768)
//   13056  : varsums float[B][K]      (768)
//   13824  : means   float[B][F][K]   (12288)
//   26624  : labels  uint8[B][L]
#define OFF_COUNTS 12288
#define OFF_VARS   13056
#define OFF_MEANS  13824
#define OFF_LABELS 26624

// ---- kA: label extraction + counts. One block per (b, channel, chunk). ----
// t is exactly one-hot -> each pixel has exactly ONE writer: no atomics on labels.
// 27648 blocks (108/CU of work): latency hidden by TLP, 1 load/thread.
__global__ __launch_bounds__(256) void ka_labels(const float* __restrict__ t,
                                                 unsigned char* __restrict__ labels,
                                                 float* __restrict__ counts) {
    const int blk = blockIdx.x;
    const int b = blk / (K * NCHUNK);
    const int rem = blk % (K * NCHUNK);
    const int c = rem / NCHUNK;
    const int chunk = rem % NCHUNK;
    const int tid = threadIdx.x;
    const int l = chunk * CHUNK + tid * 4;

    // nontemporal: t is read exactly once; don't evict x from L3
    fx4 tv = __builtin_nontemporal_load(
        &((const fx4*)t)[((size_t)(b * K + c) * L + l) >> 2]);

    int hits = 0;
    const unsigned char cc = (unsigned char)c;
    size_t base = (size_t)b * L + l;
    if (tv.x > 0.5f) { labels[base    ] = cc; ++hits; }
    if (tv.y > 0.5f) { labels[base + 1] = cc; ++hits; }
    if (tv.z > 0.5f) { labels[base + 2] = cc; ++hits; }
    if (tv.w > 0.5f) { labels[base + 3] = cc; ++hits; }

    __shared__ int red[256];
    red[tid] = hits;
    __syncthreads();
    for (int s = 128; s > 0; s >>= 1) {
        if (tid < s) red[tid] += red[tid + s];
        __syncthreads();
    }
    if (tid == 0 && red[0] > 0) atomicAdd(&counts[b * K + c], (float)red[0]);
}

// ---- kB: per-(b,f,chunk) segment sums. 18432 blocks, 2 loads/thread. ----
__global__ __launch_bounds__(256, 2) void kb_sums(const float* __restrict__ x,
                                                  const unsigned char* __restrict__ labels,
                                                  float* __restrict__ sums) {
    const int blk = blockIdx.x;
    const int b = blk / (F * NCHUNK);
    const int rem = blk % (F * NCHUNK);
    const int f = rem / NCHUNK;
    const int chunk = rem % NCHUNK;
    const int tid = threadIdx.x;
    const int w = tid >> 6;

    __shared__ float acc[4][32];
    if ((tid & 63) < 32) acc[w][tid & 63] = 0.f;

    const int l = chunk * CHUNK + tid * 4;
    uchar4 lv = *(const uchar4*)&labels[(size_t)b * L + l];
    fx4 xv = ((const fx4*)x)[((size_t)(b * F + f) * L + l) >> 2];
    __syncthreads();

    atomicAdd(&acc[w][lv.x], xv.x);
    atomicAdd(&acc[w][lv.y], xv.y);
    atomicAdd(&acc[w][lv.z], xv.z);
    atomicAdd(&acc[w][lv.w], xv.w);

    __syncthreads();
    if (tid < K) {
        float v = acc[0][tid] + acc[1][tid] + acc[2][tid] + acc[3][tid];
        atomicAdd(&sums[(b * F + f) * K + tid], v);
    }
}

// ---- k2: finalize means ----
__global__ __launch_bounds__(256) void k2_means(const float* __restrict__ sums,
                                                const float* __restrict__ counts,
                                                const int* __restrict__ ncl,
                                                float* __restrict__ means) {
    int idx = blockIdx.x * 256 + threadIdx.x;
    if (idx >= B * F * K) return;
    int b = idx / (F * K);
    int c = idx % K;
    float valid = (c < ncl[b]) ? 1.f : 0.f;
    means[idx] = sums[idx] / (counts[b * K + c] + EPSF) * valid;
}

// ---- kC: variance hinge, 1 px/thread, 16 independent scalar loads. 4608 blocks. ----
__global__ __launch_bounds__(256, 2) void kc_var(const float* __restrict__ x,
                                                 const unsigned char* __restrict__ labels,
                                                 const float* __restrict__ means,
                                                 float* __restrict__ varsums) {
    const int blk = blockIdx.x;
    const int b = blk / NSEG;
    const int seg = blk % NSEG;
    const int tid = threadIdx.x;
    const int w = tid >> 6;

    __shared__ float m[F * K];
    __shared__ float vacc[4][32];

    const int l = seg * 256 + tid;
    const int lab = labels[(size_t)b * L + l];   // issue early

    float xv[F];
    #pragma unroll
    for (int f = 0; f < F; ++f) xv[f] = x[(size_t)(b * F + f) * L + l];

    for (int i = tid; i < F * K; i += 256) m[i] = means[b * F * K + i];
    if ((tid & 63) < 32) vacc[w][tid & 63] = 0.f;
    __syncthreads();

    float d2 = 0.f;
    #pragma unroll
    for (int f = 0; f < F; ++f) {
        float u = xv[f] - m[f * K + lab];
        d2 += u * u;
    }
    float s = fmaxf(sqrtf(d2) - DELTA_VAR, 0.f);
    s *= s;
    atomicAdd(&vacc[w][lab], s);

    __syncthreads();
    if (tid < K) {
        float v = vacc[0][tid] + vacc[1][tid] + vacc[2][tid] + vacc[3][tid];
        atomicAdd(&varsums[b * K + tid], v);
    }
}

// ---- k4: combine all three terms -> scalar ----
__global__ __launch_bounds__(256) void k4_final(const float* __restrict__ means,
                                                const float* __restrict__ counts,
                                                const float* __restrict__ varsums,
                                                const int* __restrict__ ncl,
                                                float* __restrict__ out) {
    __shared__ float red[256];
    const int tid = threadIdx.x;
    float total = 0.f;
    for (int idx = tid; idx < B * K * K; idx += 256) {
        int b = idx / (K * K);
        int r = idx % (K * K);
        int c = r / K;
        int d = r % K;
        int ncb = ncl[b];
        float fnc = (float)ncb;
        if (d == 0 && c < ncb && ncb > 0) {
            float cv = varsums[b * K + c] / (counts[b * K + c] + EPSF);
            total += cv / (fnc + EPSF) * (1.0f / B);
            float m2 = 0.f;
            #pragma unroll
            for (int f = 0; f < F; ++f) {
                float mv = means[(b * F + f) * K + c];
                m2 += mv * mv;
            }
            total += GAMMA * sqrtf(m2) / fnc * (1.0f / B);
        }
        if (c != d && c < ncb && d < ncb && ncb > 1) {
            float pd2 = 0.f;
            #pragma unroll
            for (int f = 0; f < F; ++f) {
                float diff = means[(b * F + f) * K + c] - means[(b * F + f) * K + d];
                pd2 += diff * diff;
            }
            float h = fmaxf(2.f * DELTA_DIST - sqrtf(pd2), 0.f);
            total += h * h / (2.f * fnc * (fnc - 1.f) + EPSF) * (1.0f / B);
        }
    }
    red[tid] = total;
    __syncthreads();
    for (int s = 128; s > 0; s >>= 1) {
        if (tid < s) red[tid] += red[tid + s];
        __syncthreads();
    }
    if (tid == 0) out[0] = red[0];
}

extern "C" void kernel_launch(void* const* d_in, const int* in_sizes, int n_in,
                              void* d_out, int out_size, void* d_ws, size_t ws_size,
                              hipStream_t stream) {
    const float* x = (const float*)d_in[0];
    const float* t = (const float*)d_in[1];
    const int* ncl = (const int*)d_in[2];
    float* out = (float*)d_out;

    char* ws = (char*)d_ws;
    float* sums = (float*)ws;
    float* counts = (float*)(ws + OFF_COUNTS);
    float* varsums = (float*)(ws + OFF_VARS);
    float* means = (float*)(ws + OFF_MEANS);
    unsigned char* labels = (unsigned char*)(ws + OFF_LABELS);

    (void)hipMemsetAsync(ws, 0, OFF_MEANS, stream);

    ka_labels<<<B * K * NCHUNK, 256, 0, stream>>>(t, labels, counts);
    kb_sums<<<B * F * NCHUNK, 256, 0, stream>>>(x, labels, sums);
    k2_means<<<(B * F * K + 255) / 256, 256, 0, stream>>>(sums, counts, ncl, means);
    kc_var<<<B * NSEG, 256, 0, stream>>>(x, labels, means, varsums);
    k4_final<<<1, 256, 0, stream>>>(means, counts, varsums, ncl, out);
}

// Round 5
// 311.963 us; speedup vs baseline: 1.3021x; 1.3021x over previous
//
#include <hip/hip_runtime.h>

#define B 8
#define F 16
#define K 24
#define L 147456            // 384*384
#define NSEG (L / 256)      // 576 segments of 256 px
#define NBLK 144            // kb2 blocks per batch
#define EPSF 1e-8f
#define DELTA_VAR 0.5f
#define DELTA_DIST 1.5f
#define GAMMA 0.001f

typedef float fx4 __attribute__((ext_vector_type(4)));
typedef short bf16x8 __attribute__((ext_vector_type(8)));   // MFMA A/B frag (4 VGPRs)
typedef float f32x4 __attribute__((ext_vector_type(4)));    // MFMA C/D frag

// Workspace layout (bytes):
//   0      : sums    float[B][F][K]   (12288)
//   12288  : counts  float[B][K]      (768)
//   13056  : varsums float[B][K]      (768)
//   13824  : means   float[B][F][K]   (12288)
//   26624  : labels  uint8[B][L]
#define OFF_COUNTS 12288
#define OFF_VARS   13056
#define OFF_MEANS  13824
#define OFF_LABELS 26624

__device__ __forceinline__ short to_bf16(float v) {
    unsigned u = __float_as_uint(v);
    return (short)((u + 0x7FFFu + ((u >> 16) & 1u)) >> 16);   // RNE
}

// ---- kA: labels + counts. 1 px/thread, 24 coalesced channel loads. ----
__global__ __launch_bounds__(256) void ka_labels(const float* __restrict__ t,
                                                 unsigned char* __restrict__ labels,
                                                 float* __restrict__ counts) {
    const int blk = blockIdx.x;
    const int b = blk / NSEG;
    const int seg = blk % NSEG;
    const int tid = threadIdx.x;
    const int l = seg * 256 + tid;

    int lab = 0;
    #pragma unroll
    for (int c = 0; c < K; ++c) {
        float tv = __builtin_nontemporal_load(&t[(size_t)(b * K + c) * L + l]);
        lab += c * (tv > 0.5f);
    }
    labels[(size_t)b * L + l] = (unsigned char)lab;

    __shared__ float cnt[32];
    if (tid < 32) cnt[tid] = 0.f;
    __syncthreads();
    atomicAdd(&cnt[lab], 1.f);
    __syncthreads();
    if (tid < K) atomicAdd(&counts[b * K + tid], cnt[tid]);
}

// ---- kB: segment sums as MFMA GEMM: sums[f,c] = x(16xL) @ onehot(Lx24). ----
// Zero LDS atomics. A = bf16(x), B = one-hot from labels (exact in bf16).
// Layouts (verified per guide m89/m91/m120): A[m=lane&15][k=q*8+j],
// B[k=q*8+j][n=lane&15], D reg r @ lane = C[m=q*4+r][n=lane&15].
__global__ __launch_bounds__(256) void kb_mfma(const float* __restrict__ x,
                                               const unsigned char* __restrict__ labels,
                                               float* __restrict__ sums) {
    const int b = blockIdx.x / NBLK;
    const int blk = blockIdx.x % NBLK;
    const int tid = threadIdx.x;
    const int wave = tid >> 6;
    const int lane = tid & 63;
    const int n = lane & 15;       // A-row (f) and B-col (c) position
    const int q = lane >> 4;       // quad
    const int wid = blk * 4 + wave;   // 0..575, each wave: 8 chunks of 32 px

    f32x4 acc0 = {0.f, 0.f, 0.f, 0.f};
    f32x4 acc1 = {0.f, 0.f, 0.f, 0.f};
    const float* xr_base = x + (size_t)(b * F + n) * L + q * 8;
    const unsigned char* lb_base = labels + (size_t)b * L + q * 8;

    #pragma unroll 2
    for (int it = 0; it < 8; ++it) {
        const int px0 = (wid * 8 + it) * 32;
        // A: 8 consecutive fp32 of row f=n  (wave covers 16 rows x 128B — coalesced)
        fx4 xa = *(const fx4*)(xr_base + px0);
        fx4 xc = *(const fx4*)(xr_base + px0 + 4);
        // labels for k-slice q*8..q*8+7 (same 8B broadcast to 16 lanes)
        const unsigned* lp = (const unsigned*)(lb_base + px0);
        unsigned l0 = lp[0], l1 = lp[1];

        bf16x8 afrag;
        afrag[0] = to_bf16(xa.x); afrag[1] = to_bf16(xa.y);
        afrag[2] = to_bf16(xa.z); afrag[3] = to_bf16(xa.w);
        afrag[4] = to_bf16(xc.x); afrag[5] = to_bf16(xc.y);
        afrag[6] = to_bf16(xc.z); afrag[7] = to_bf16(xc.w);

        bf16x8 bf0, bf1;   // one-hot column n (tile0: c=n, tile1: c=16+n)
        #pragma unroll
        for (int j = 0; j < 8; ++j) {
            int lj = (j < 4) ? ((l0 >> (8 * j)) & 0xFF) : ((l1 >> (8 * (j - 4))) & 0xFF);
            bf0[j] = (lj == n)      ? (short)0x3F80 : (short)0;
            bf1[j] = (lj == n + 16) ? (short)0x3F80 : (short)0;
        }
        acc0 = __builtin_amdgcn_mfma_f32_16x16x32_bf16(afrag, bf0, acc0, 0, 0, 0);
        acc1 = __builtin_amdgcn_mfma_f32_16x16x32_bf16(afrag, bf1, acc1, 0, 0, 0);
    }

    // write-out: distinct (f,c) per lane/reg within a wave -> contention-free-ish
    #pragma unroll
    for (int r = 0; r < 4; ++r) {
        int f = q * 4 + r;
        atomicAdd(&sums[(b * F + f) * K + n], acc0[r]);
        if (n < 8) atomicAdd(&sums[(b * F + f) * K + 16 + n], acc1[r]);
    }
}

// ---- k2: finalize means ----
__global__ __launch_bounds__(256) void k2_means(const float* __restrict__ sums,
                                                const float* __restrict__ counts,
                                                const int* __restrict__ ncl,
                                                float* __restrict__ means) {
    int idx = blockIdx.x * 256 + threadIdx.x;
    if (idx >= B * F * K) return;
    int b = idx / (F * K);
    int c = idx % K;
    float valid = (c < ncl[b]) ? 1.f : 0.f;
    means[idx] = sums[idx] / (counts[b * K + c] + EPSF) * valid;
}

// ---- kC: variance hinge, 1 px/thread. Only 1.18M LDS atomics (negligible). ----
__global__ __launch_bounds__(256, 2) void kc_var(const float* __restrict__ x,
                                                 const unsigned char* __restrict__ labels,
                                                 const float* __restrict__ means,
                                                 float* __restrict__ varsums) {
    const int blk = blockIdx.x;
    const int b = blk / NSEG;
    const int seg = blk % NSEG;
    const int tid = threadIdx.x;
    const int w = tid >> 6;

    __shared__ float m[F * K];
    __shared__ float vacc[4][32];

    const int l = seg * 256 + tid;
    const int lab = labels[(size_t)b * L + l];

    float xv[F];
    #pragma unroll
    for (int f = 0; f < F; ++f) xv[f] = x[(size_t)(b * F + f) * L + l];

    for (int i = tid; i < F * K; i += 256) m[i] = means[b * F * K + i];
    if ((tid & 63) < 32) vacc[w][tid & 63] = 0.f;
    __syncthreads();

    float d2 = 0.f;
    #pragma unroll
    for (int f = 0; f < F; ++f) {
        float u = xv[f] - m[f * K + lab];
        d2 += u * u;
    }
    float s = fmaxf(sqrtf(d2) - DELTA_VAR, 0.f);
    s *= s;
    atomicAdd(&vacc[w][lab], s);

    __syncthreads();
    if (tid < K) {
        float v = vacc[0][tid] + vacc[1][tid] + vacc[2][tid] + vacc[3][tid];
        atomicAdd(&varsums[b * K + tid], v);
    }
}

// ---- k4: combine all three terms -> scalar ----
__global__ __launch_bounds__(256) void k4_final(const float* __restrict__ means,
                                                const float* __restrict__ counts,
                                                const float* __restrict__ varsums,
                                                const int* __restrict__ ncl,
                                                float* __restrict__ out) {
    __shared__ float red[256];
    const int tid = threadIdx.x;
    float total = 0.f;
    for (int idx = tid; idx < B * K * K; idx += 256) {
        int b = idx / (K * K);
        int r = idx % (K * K);
        int c = r / K;
        int d = r % K;
        int ncb = ncl[b];
        float fnc = (float)ncb;
        if (d == 0 && c < ncb && ncb > 0) {
            float cv = varsums[b * K + c] / (counts[b * K + c] + EPSF);
            total += cv / (fnc + EPSF) * (1.0f / B);
            float m2 = 0.f;
            #pragma unroll
            for (int f = 0; f < F; ++f) {
                float mv = means[(b * F + f) * K + c];
                m2 += mv * mv;
            }
            total += GAMMA * sqrtf(m2) / fnc * (1.0f / B);
        }
        if (c != d && c < ncb && d < ncb && ncb > 1) {
            float pd2 = 0.f;
            #pragma unroll
            for (int f = 0; f < F; ++f) {
                float diff = means[(b * F + f) * K + c] - means[(b * F + f) * K + d];
                pd2 += diff * diff;
            }
            float h = fmaxf(2.f * DELTA_DIST - sqrtf(pd2), 0.f);
            total += h * h / (2.f * fnc * (fnc - 1.f) + EPSF) * (1.0f / B);
        }
    }
    red[tid] = total;
    __syncthreads();
    for (int s = 128; s > 0; s >>= 1) {
        if (tid < s) red[tid] += red[tid + s];
        __syncthreads();
    }
    if (tid == 0) out[0] = red[0];
}

extern "C" void kernel_launch(void* const* d_in, const int* in_sizes, int n_in,
                              void* d_out, int out_size, void* d_ws, size_t ws_size,
                              hipStream_t stream) {
    const float* x = (const float*)d_in[0];
    const float* t = (const float*)d_in[1];
    const int* ncl = (const int*)d_in[2];
    float* out = (float*)d_out;

    char* ws = (char*)d_ws;
    float* sums = (float*)ws;
    float* counts = (float*)(ws + OFF_COUNTS);
    float* varsums = (float*)(ws + OFF_VARS);
    float* means = (float*)(ws + OFF_MEANS);
    unsigned char* labels = (unsigned char*)(ws + OFF_LABELS);

    (void)hipMemsetAsync(ws, 0, OFF_MEANS, stream);

    ka_labels<<<B * NSEG, 256, 0, stream>>>(t, labels, counts);
    kb_mfma<<<B * NBLK, 256, 0, stream>>>(x, labels, sums);
    k2_means<<<(B * F * K + 255) / 256, 256, 0, stream>>>(sums, counts, ncl, means);
    kc_var<<<B * NSEG, 256, 0, stream>>>(x, labels, means, varsums);
    k4_final<<<1, 256, 0, stream>>>(means, counts, varsums, ncl, out);
}

// Round 6
// 259.898 us; speedup vs baseline: 1.5629x; 1.2003x over previous
//
#include <hip/hip_runtime.h>

#define B 8
#define F 16
#define K 24
#define L 147456            // 384*384
#define NSEG (L / 256)      // 576 segments of 256 px per batch (ka/kc grids)
#define NBLKB 288           // kb blocks per batch
#define KB_ITER 4           // 32-px MFMA steps per wave in kb
#define EPSF 1e-8f
#define DELTA_VAR 0.5f
#define DELTA_DIST 1.5f
#define GAMMA 0.001f

typedef float fx4 __attribute__((ext_vector_type(4)));
typedef short bf16x8 __attribute__((ext_vector_type(8)));
typedef float f32x4 __attribute__((ext_vector_type(4)));

// ---- Workspace layout (bytes). NO global atomics anywhere: every block owns
// a unique partial slot; tiny reducers combine. Nothing needs pre-zeroing.
//   sum_part  float[B*NBLKB][F*K]  @ 0         : 2304*384*4 = 3,538,944
//   cnt_part  float[B*NSEG][K]     @ 3538944   : 4608*24*4  =   442,368
//   var_part  float[B*NSEG][K]     @ 3981312   : 442,368
//   counts    float[B*K]           @ 4423680   : 768
//   varsums   float[B*K]           @ 4424448   : 768
//   means     float[B*F*K]         @ 4425216   : 12,288
//   labels    uint8[B*L]           @ 4437504   : 1,179,648  -> total 5,617,152
#define OFF_CNTP 3538944
#define OFF_VARP 3981312
#define OFF_CNT  4423680
#define OFF_VSUM 4424448
#define OFF_MEAN 4425216
#define OFF_LAB  4437504

__device__ __forceinline__ short to_bf16(float v) {
    unsigned u = __float_as_uint(v);
    return (short)((u + 0x7FFFu + ((u >> 16) & 1u)) >> 16);   // RNE
}

// ---- kA: labels + per-block count partials. 1 px/thread, 24 coalesced loads. ----
__global__ __launch_bounds__(256) void ka_labels(const float* __restrict__ t,
                                                 unsigned char* __restrict__ labels,
                                                 float* __restrict__ cnt_part) {
    const int blk = blockIdx.x;          // = b*NSEG + seg
    const int b = blk / NSEG;
    const int seg = blk % NSEG;
    const int tid = threadIdx.x;
    const int l = seg * 256 + tid;

    int lab = 0;
    #pragma unroll
    for (int c = 0; c < K; ++c) {
        float tv = __builtin_nontemporal_load(&t[(size_t)(b * K + c) * L + l]);
        lab += c * (tv > 0.5f);
    }
    labels[(size_t)b * L + l] = (unsigned char)lab;

    __shared__ float cnt[32];
    if (tid < 32) cnt[tid] = 0.f;
    __syncthreads();
    atomicAdd(&cnt[lab], 1.f);           // LDS atomic: 256/block, negligible
    __syncthreads();
    if (tid < K) cnt_part[blk * K + tid] = cnt[tid];   // unique slot, plain store
}

// ---- kr24: reduce part[B*NSEG][24] -> out[B*24]. 192 blocks. ----
__global__ __launch_bounds__(256) void kr_reduce24(const float* __restrict__ part,
                                                   float* __restrict__ out) {
    const int bc = blockIdx.x;           // b*24 + c
    const int b = bc / K;
    const int c = bc % K;
    const int tid = threadIdx.x;
    float s = 0.f;
    for (int j = tid; j < NSEG; j += 256) s += part[(b * NSEG + j) * K + c];
    __shared__ float red[256];
    red[tid] = s;
    __syncthreads();
    for (int st = 128; st > 0; st >>= 1) {
        if (tid < st) red[tid] += red[tid + st];
        __syncthreads();
    }
    if (tid == 0) out[bc] = red[0];
}

// ---- kB: segment sums via MFMA, per-block partial stores (NO global atomics). ----
// Layouts verified (absmax 0.0 in R5): A[m=lane&15][k=q*8+j], B[k][n=lane&15],
// D reg r = C[m=q*4+r][n].  sums[f,c] = x(16xL) @ onehot(Lx24).
__global__ __launch_bounds__(256) void kb_mfma(const float* __restrict__ x,
                                               const unsigned char* __restrict__ labels,
                                               float* __restrict__ sum_part) {
    const int gblk = blockIdx.x;
    const int b = gblk / NBLKB;
    const int blk = gblk % NBLKB;
    const int tid = threadIdx.x;
    const int wave = tid >> 6;
    const int lane = tid & 63;
    const int n = lane & 15;
    const int q = lane >> 4;
    const int wid = blk * 4 + wave;      // 0..1151 per batch

    f32x4 acc0 = {0.f, 0.f, 0.f, 0.f};
    f32x4 acc1 = {0.f, 0.f, 0.f, 0.f};
    const float* xr_base = x + (size_t)(b * F + n) * L + q * 8;
    const unsigned char* lb_base = labels + (size_t)b * L + q * 8;

    #pragma unroll
    for (int it = 0; it < KB_ITER; ++it) {
        const int px0 = (wid * KB_ITER + it) * 32;
        fx4 xa = *(const fx4*)(xr_base + px0);
        fx4 xc = *(const fx4*)(xr_base + px0 + 4);
        const unsigned* lp = (const unsigned*)(lb_base + px0);
        unsigned l0 = lp[0], l1 = lp[1];

        bf16x8 afrag;
        afrag[0] = to_bf16(xa.x); afrag[1] = to_bf16(xa.y);
        afrag[2] = to_bf16(xa.z); afrag[3] = to_bf16(xa.w);
        afrag[4] = to_bf16(xc.x); afrag[5] = to_bf16(xc.y);
        afrag[6] = to_bf16(xc.z); afrag[7] = to_bf16(xc.w);

        bf16x8 bf0, bf1;
        #pragma unroll
        for (int j = 0; j < 8; ++j) {
            int lj = (j < 4) ? ((l0 >> (8 * j)) & 0xFF) : ((l1 >> (8 * (j - 4))) & 0xFF);
            bf0[j] = (lj == n)      ? (short)0x3F80 : (short)0;
            bf1[j] = (lj == n + 16) ? (short)0x3F80 : (short)0;
        }
        acc0 = __builtin_amdgcn_mfma_f32_16x16x32_bf16(afrag, bf0, acc0, 0, 0, 0);
        acc1 = __builtin_amdgcn_mfma_f32_16x16x32_bf16(afrag, bf1, acc1, 0, 0, 0);
    }

    // combine 4 waves in LDS (plain writes, unique slots), store block partial
    __shared__ float sacc[4][F * K];
    #pragma unroll
    for (int r = 0; r < 4; ++r) {
        int f = q * 4 + r;
        sacc[wave][f * K + n] = acc0[r];
        if (n < 8) sacc[wave][f * K + 16 + n] = acc1[r];
    }
    __syncthreads();
    for (int i = tid; i < F * K; i += 256) {
        float v = sacc[0][i] + sacc[1][i] + sacc[2][i] + sacc[3][i];
        sum_part[(size_t)gblk * (F * K) + i] = v;     // coalesced plain store
    }
}

// ---- k2: reduce sum_part -> means (with counts & valid mask). 12 blocks. ----
__global__ __launch_bounds__(256) void k2_means(const float* __restrict__ sum_part,
                                                const float* __restrict__ counts,
                                                const int* __restrict__ ncl,
                                                float* __restrict__ means) {
    const int idx = blockIdx.x * 256 + threadIdx.x;   // (b, f*24+c) over 3072
    if (idx >= B * F * K) return;
    const int b = idx / (F * K);
    const int r = idx % (F * K);
    const int c = r % K;

    float s = 0.f;
    const float* base = sum_part + (size_t)b * NBLKB * (F * K) + r;
    #pragma unroll 4
    for (int j = 0; j < NBLKB; ++j) s += base[(size_t)j * (F * K)];

    float valid = (c < ncl[b]) ? 1.f : 0.f;
    means[idx] = s / (counts[b * K + c] + EPSF) * valid;
}

// ---- kC: variance hinge, 1 px/thread, per-block partial stores. ----
__global__ __launch_bounds__(256, 2) void kc_var(const float* __restrict__ x,
                                                 const unsigned char* __restrict__ labels,
                                                 const float* __restrict__ means,
                                                 float* __restrict__ var_part) {
    const int blk = blockIdx.x;
    const int b = blk / NSEG;
    const int seg = blk % NSEG;
    const int tid = threadIdx.x;
    const int w = tid >> 6;

    __shared__ float m[F * K];
    __shared__ float vacc[4][32];

    const int l = seg * 256 + tid;
    const int lab = labels[(size_t)b * L + l];

    float xv[F];
    #pragma unroll
    for (int f = 0; f < F; ++f) xv[f] = x[(size_t)(b * F + f) * L + l];

    for (int i = tid; i < F * K; i += 256) m[i] = means[b * F * K + i];
    if ((tid & 63) < 32) vacc[w][tid & 63] = 0.f;
    __syncthreads();

    float d2 = 0.f;
    #pragma unroll
    for (int f = 0; f < F; ++f) {
        float u = xv[f] - m[f * K + lab];
        d2 += u * u;
    }
    float s = fmaxf(sqrtf(d2) - DELTA_VAR, 0.f);
    s *= s;
    atomicAdd(&vacc[w][lab], s);         // LDS atomic only

    __syncthreads();
    if (tid < K) {
        float v = vacc[0][tid] + vacc[1][tid] + vacc[2][tid] + vacc[3][tid];
        var_part[blk * K + tid] = v;     // unique slot, plain store
    }
}

// ---- k4: combine terms -> scalar ----
__global__ __launch_bounds__(256) void k4_final(const float* __restrict__ means,
                                                const float* __restrict__ counts,
                                                const float* __restrict__ varsums,
                                                const int* __restrict__ ncl,
                                                float* __restrict__ out) {
    __shared__ float red[256];
    const int tid = threadIdx.x;
    float total = 0.f;
    for (int idx = tid; idx < B * K * K; idx += 256) {
        int b = idx / (K * K);
        int r = idx % (K * K);
        int c = r / K;
        int d = r % K;
        int ncb = ncl[b];
        float fnc = (float)ncb;
        if (d == 0 && c < ncb && ncb > 0) {
            float cv = varsums[b * K + c] / (counts[b * K + c] + EPSF);
            total += cv / (fnc + EPSF) * (1.0f / B);
            float m2 = 0.f;
            #pragma unroll
            for (int f = 0; f < F; ++f) {
                float mv = means[(b * F + f) * K + c];
                m2 += mv * mv;
            }
            total += GAMMA * sqrtf(m2) / fnc * (1.0f / B);
        }
        if (c != d && c < ncb && d < ncb && ncb > 1) {
            float pd2 = 0.f;
            #pragma unroll
            for (int f = 0; f < F; ++f) {
                float diff = means[(b * F + f) * K + c] - means[(b * F + f) * K + d];
                pd2 += diff * diff;
            }
            float h = fmaxf(2.f * DELTA_DIST - sqrtf(pd2), 0.f);
            total += h * h / (2.f * fnc * (fnc - 1.f) + EPSF) * (1.0f / B);
        }
    }
    red[tid] = total;
    __syncthreads();
    for (int s = 128; s > 0; s >>= 1) {
        if (tid < s) red[tid] += red[tid + s];
        __syncthreads();
    }
    if (tid == 0) out[0] = red[0];
}

extern "C" void kernel_launch(void* const* d_in, const int* in_sizes, int n_in,
                              void* d_out, int out_size, void* d_ws, size_t ws_size,
                              hipStream_t stream) {
    const float* x = (const float*)d_in[0];
    const float* t = (const float*)d_in[1];
    const int* ncl = (const int*)d_in[2];
    float* out = (float*)d_out;

    char* ws = (char*)d_ws;
    float* sum_part = (float*)ws;
    float* cnt_part = (float*)(ws + OFF_CNTP);
    float* var_part = (float*)(ws + OFF_VARP);
    float* counts   = (float*)(ws + OFF_CNT);
    float* varsums  = (float*)(ws + OFF_VSUM);
    float* means    = (float*)(ws + OFF_MEAN);
    unsigned char* labels = (unsigned char*)(ws + OFF_LAB);

    ka_labels <<<B * NSEG, 256, 0, stream>>>(t, labels, cnt_part);
    kr_reduce24<<<B * K, 256, 0, stream>>>(cnt_part, counts);
    kb_mfma   <<<B * NBLKB, 256, 0, stream>>>(x, labels, sum_part);
    k2_means  <<<(B * F * K + 255) / 256, 256, 0, stream>>>(sum_part, counts, ncl, means);
    kc_var    <<<B * NSEG, 256, 0, stream>>>(x, labels, means, var_part);
    kr_reduce24<<<B * K, 256, 0, stream>>>(var_part, varsums);
    k4_final  <<<1, 256, 0, stream>>>(means, counts, varsums, ncl, out);
}

// Round 7
// 257.429 us; speedup vs baseline: 1.5779x; 1.0096x over previous
//
#include <hip/hip_runtime.h>

#define B 8
#define F 16
#define K 24
#define L 147456            // 384*384
#define CHUNK1 1024         // k1: pixels per block
#define NCH1 (L / CHUNK1)   // 144
#define NSEG (L / 256)      // 576, kc
#define EPSF 1e-8f
#define DELTA_VAR 0.5f
#define DELTA_DIST 1.5f
#define GAMMA 0.001f

typedef float fx4 __attribute__((ext_vector_type(4)));
typedef short bf16x8 __attribute__((ext_vector_type(8)));
typedef float f32x4 __attribute__((ext_vector_type(4)));

// ---- Workspace (bytes), no global atomics anywhere ----
//   sum_part float[B*NCH1][F*K]      @ 0        : 1152*384*4 = 1,769,472
//   cnt_part float[K][B*NCH1]        @ 1769472  : 110,592   (transposed!)
//   var_part float[K][B*NSEG]        @ 1880064  : 442,368   (transposed!)
//   counts   float[B*K]              @ 2322432  : 768
//   varsums  float[B*K]              @ 2323200  : 768
//   means    float[B*F*K]            @ 2323968  : 12,288
//   labels   uint8[B*L]              @ 2336256  : 1,179,648
#define OFF_CNTP 1769472
#define OFF_VARP 1880064
#define OFF_CNT  2322432
#define OFF_VSUM 2323200
#define OFF_MEAN 2323968
#define OFF_LAB  2336256

__device__ __forceinline__ short to_bf16(float v) {
    unsigned u = __float_as_uint(v);
    return (short)((u + 0x7FFFu + ((u >> 16) & 1u)) >> 16);   // RNE
}

// ---- K1: fused labels + counts + MFMA segment-sums. One pass over t AND x. ----
__global__ __launch_bounds__(256) void k1_fused(const float* __restrict__ t,
                                                const float* __restrict__ x,
                                                unsigned char* __restrict__ labels,
                                                float* __restrict__ cnt_part,
                                                float* __restrict__ sum_part) {
    const int gblk = blockIdx.x;          // b*NCH1 + ch
    const int b = gblk / NCH1;
    const int ch = gblk % NCH1;
    const int tid = threadIdx.x;
    const int wave = tid >> 6;
    const int lane = tid & 63;

    __shared__ unsigned char slab[CHUNK1];
    __shared__ float hist[4][32];
    __shared__ float sacc[4][F * K];

    if (lane < 32) hist[wave][lane] = 0.f;

    // ---- label phase: 4 px/thread, 24 independent float4 NT loads ----
    const int px = ch * CHUNK1 + tid * 4;
    const fx4* t4 = (const fx4*)t;
    int lab0 = 0, lab1 = 0, lab2 = 0, lab3 = 0;
    #pragma unroll
    for (int c = 0; c < K; ++c) {
        fx4 tv = __builtin_nontemporal_load(&t4[((size_t)(b * K + c) * L + px) >> 2]);
        lab0 += c * (tv.x > 0.5f);
        lab1 += c * (tv.y > 0.5f);
        lab2 += c * (tv.z > 0.5f);
        lab3 += c * (tv.w > 0.5f);
    }
    uchar4 lv = make_uchar4((unsigned char)lab0, (unsigned char)lab1,
                            (unsigned char)lab2, (unsigned char)lab3);
    *(uchar4*)&labels[(size_t)b * L + px] = lv;          // for kc
    *(uchar4*)&slab[tid * 4] = lv;                       // for MFMA phase
    atomicAdd(&hist[wave][lab0], 1.f);                   // wave-local LDS
    atomicAdd(&hist[wave][lab1], 1.f);
    atomicAdd(&hist[wave][lab2], 1.f);
    atomicAdd(&hist[wave][lab3], 1.f);
    __syncthreads();

    // counts partial (transposed layout: row c contiguous over gblk)
    if (tid < K) {
        float v = hist[0][tid] + hist[1][tid] + hist[2][tid] + hist[3][tid];
        cnt_part[tid * (B * NCH1) + gblk] = v;
    }

    // ---- MFMA phase: wave handles 256 px = 8 k-steps of 32 ----
    // Layouts (verified absmax 0.0 R5/R6): A[m=lane&15][k=q*8+j],
    // B[k=q*8+j][n=lane&15], D reg r = C[m=q*4+r][n].
    const int n = lane & 15;
    const int q = lane >> 4;
    f32x4 acc0 = {0.f, 0.f, 0.f, 0.f};
    f32x4 acc1 = {0.f, 0.f, 0.f, 0.f};
    const float* xr = x + (size_t)(b * F + n) * L + ch * CHUNK1 + wave * 256 + q * 8;
    const unsigned char* sl = slab + wave * 256 + q * 8;

    #pragma unroll 2
    for (int it = 0; it < 8; ++it) {
        fx4 xa = *(const fx4*)(xr + it * 32);
        fx4 xc = *(const fx4*)(xr + it * 32 + 4);
        unsigned l0 = *(const unsigned*)(sl + it * 32);
        unsigned l1 = *(const unsigned*)(sl + it * 32 + 4);

        bf16x8 afrag;
        afrag[0] = to_bf16(xa.x); afrag[1] = to_bf16(xa.y);
        afrag[2] = to_bf16(xa.z); afrag[3] = to_bf16(xa.w);
        afrag[4] = to_bf16(xc.x); afrag[5] = to_bf16(xc.y);
        afrag[6] = to_bf16(xc.z); afrag[7] = to_bf16(xc.w);

        bf16x8 bf0, bf1;
        #pragma unroll
        for (int j = 0; j < 8; ++j) {
            int lj = (j < 4) ? ((l0 >> (8 * j)) & 0xFF) : ((l1 >> (8 * (j - 4))) & 0xFF);
            bf0[j] = (lj == n)      ? (short)0x3F80 : (short)0;
            bf1[j] = (lj == n + 16) ? (short)0x3F80 : (short)0;
        }
        acc0 = __builtin_amdgcn_mfma_f32_16x16x32_bf16(afrag, bf0, acc0, 0, 0, 0);
        acc1 = __builtin_amdgcn_mfma_f32_16x16x32_bf16(afrag, bf1, acc1, 0, 0, 0);
    }

    #pragma unroll
    for (int r = 0; r < 4; ++r) {
        int f = q * 4 + r;
        sacc[wave][f * K + n] = acc0[r];
        if (n < 8) sacc[wave][f * K + 16 + n] = acc1[r];
    }
    __syncthreads();
    for (int i = tid; i < F * K; i += 256) {
        float v = sacc[0][i] + sacc[1][i] + sacc[2][i] + sacc[3][i];
        sum_part[(size_t)gblk * (F * K) + i] = v;
    }
}

// ---- K2: counts + means, one block per batch ----
__global__ __launch_bounds__(256) void k2_means(const float* __restrict__ cnt_part,
                                                const float* __restrict__ sum_part,
                                                const int* __restrict__ ncl,
                                                float* __restrict__ counts,
                                                float* __restrict__ means) {
    const int b = blockIdx.x;
    const int tid = threadIdx.x;
    __shared__ float cl[8][K];
    __shared__ float cs[K];

    // counts: 24 rows x 144 contiguous; tid<192: c=tid>>3, grp=tid&7 sums 18
    if (tid < 192) {
        int c = tid >> 3, grp = tid & 7;
        const float* row = cnt_part + c * (B * NCH1) + b * NCH1 + grp * 18;
        float s = 0.f;
        #pragma unroll
        for (int j = 0; j < 18; ++j) s += row[j];
        cl[grp][c] = s;
    }
    __syncthreads();
    if (tid < K) {
        float s = 0.f;
        #pragma unroll
        for (int g = 0; g < 8; ++g) s += cl[g][tid];
        cs[tid] = s;
        counts[b * K + tid] = s;
    }
    __syncthreads();

    const int ncb = ncl[b];
    for (int r = tid; r < F * K; r += 256) {
        float s = 0.f;
        const float* base = sum_part + (size_t)b * NCH1 * (F * K) + r;
        #pragma unroll 4
        for (int j = 0; j < NCH1; ++j) s += base[(size_t)j * (F * K)];
        int c = r % K;
        float valid = (c < ncb) ? 1.f : 0.f;
        means[b * F * K + r] = s / (cs[c] + EPSF) * valid;
    }
}

// ---- kC: variance hinge, 1 px/thread, transposed partial stores ----
__global__ __launch_bounds__(256, 2) void kc_var(const float* __restrict__ x,
                                                 const unsigned char* __restrict__ labels,
                                                 const float* __restrict__ means,
                                                 float* __restrict__ var_part) {
    const int blk = blockIdx.x;
    const int b = blk / NSEG;
    const int seg = blk % NSEG;
    const int tid = threadIdx.x;
    const int w = tid >> 6;

    __shared__ float m[F * K];
    __shared__ float vacc[4][32];

    const int l = seg * 256 + tid;
    const int lab = labels[(size_t)b * L + l];

    float xv[F];
    #pragma unroll
    for (int f = 0; f < F; ++f) xv[f] = x[(size_t)(b * F + f) * L + l];

    for (int i = tid; i < F * K; i += 256) m[i] = means[b * F * K + i];
    if ((tid & 63) < 32) vacc[w][tid & 63] = 0.f;
    __syncthreads();

    float d2 = 0.f;
    #pragma unroll
    for (int f = 0; f < F; ++f) {
        float u = xv[f] - m[f * K + lab];
        d2 += u * u;
    }
    float s = fmaxf(sqrtf(d2) - DELTA_VAR, 0.f);
    s *= s;
    atomicAdd(&vacc[w][lab], s);

    __syncthreads();
    if (tid < K) {
        float v = vacc[0][tid] + vacc[1][tid] + vacc[2][tid] + vacc[3][tid];
        var_part[tid * (B * NSEG) + blk] = v;   // transposed: row c contiguous
    }
}

// ---- kr: reduce var_part rows (576 contiguous floats) -> varsums ----
__global__ __launch_bounds__(256) void kr_reduce(const float* __restrict__ part,
                                                 float* __restrict__ out) {
    const int bc = blockIdx.x;           // b*K + c
    const int b = bc / K;
    const int c = bc % K;
    const int tid = threadIdx.x;
    const float* row = part + c * (B * NSEG) + b * NSEG;
    float s = 0.f;
    for (int j = tid; j < NSEG; j += 256) s += row[j];
    __shared__ float red[256];
    red[tid] = s;
    __syncthreads();
    for (int st = 128; st > 0; st >>= 1) {
        if (tid < st) red[tid] += red[tid + st];
        __syncthreads();
    }
    if (tid == 0) out[bc] = red[0];
}

// ---- k4: combine terms -> scalar ----
__global__ __launch_bounds__(256) void k4_final(const float* __restrict__ means,
                                                const float* __restrict__ counts,
                                                const float* __restrict__ varsums,
                                                const int* __restrict__ ncl,
                                                float* __restrict__ out) {
    __shared__ float red[256];
    const int tid = threadIdx.x;
    float total = 0.f;
    for (int idx = tid; idx < B * K * K; idx += 256) {
        int b = idx / (K * K);
        int r = idx % (K * K);
        int c = r / K;
        int d = r % K;
        int ncb = ncl[b];
        float fnc = (float)ncb;
        if (d == 0 && c < ncb && ncb > 0) {
            float cv = varsums[b * K + c] / (counts[b * K + c] + EPSF);
            total += cv / (fnc + EPSF) * (1.0f / B);
            float m2 = 0.f;
            #pragma unroll
            for (int f = 0; f < F; ++f) {
                float mv = means[(b * F + f) * K + c];
                m2 += mv * mv;
            }
            total += GAMMA * sqrtf(m2) / fnc * (1.0f / B);
        }
        if (c != d && c < ncb && d < ncb && ncb > 1) {
            float pd2 = 0.f;
            #pragma unroll
            for (int f = 0; f < F; ++f) {
                float diff = means[(b * F + f) * K + c] - means[(b * F + f) * K + d];
                pd2 += diff * diff;
            }
            float h = fmaxf(2.f * DELTA_DIST - sqrtf(pd2), 0.f);
            total += h * h / (2.f * fnc * (fnc - 1.f) + EPSF) * (1.0f / B);
        }
    }
    red[tid] = total;
    __syncthreads();
    for (int s = 128; s > 0; s >>= 1) {
        if (tid < s) red[tid] += red[tid + s];
        __syncthreads();
    }
    if (tid == 0) out[0] = red[0];
}

extern "C" void kernel_launch(void* const* d_in, const int* in_sizes, int n_in,
                              void* d_out, int out_size, void* d_ws, size_t ws_size,
                              hipStream_t stream) {
    const float* x = (const float*)d_in[0];
    const float* t = (const float*)d_in[1];
    const int* ncl = (const int*)d_in[2];
    float* out = (float*)d_out;

    char* ws = (char*)d_ws;
    float* sum_part = (float*)ws;
    float* cnt_part = (float*)(ws + OFF_CNTP);
    float* var_part = (float*)(ws + OFF_VARP);
    float* counts   = (float*)(ws + OFF_CNT);
    float* varsums  = (float*)(ws + OFF_VSUM);
    float* means    = (float*)(ws + OFF_MEAN);
    unsigned char* labels = (unsigned char*)(ws + OFF_LAB);

    k1_fused <<<B * NCH1, 256, 0, stream>>>(t, x, labels, cnt_part, sum_part);
    k2_means <<<B, 256, 0, stream>>>(cnt_part, sum_part, ncl, counts, means);
    kc_var   <<<B * NSEG, 256, 0, stream>>>(x, labels, means, var_part);
    kr_reduce<<<B * K, 256, 0, stream>>>(var_part, varsums);
    k4_final <<<1, 256, 0, stream>>>(means, counts, varsums, ncl, out);
}